// Round 9
// baseline (144.634 us; speedup 1.0000x reference)
//
#include <hip/hip_runtime.h>
#include <hip/hip_bf16.h>
#include <hip/hip_cooperative_groups.h>

namespace cg = cooperative_groups;

#define NN    2048
#define DDIM  128
#define HH    8
#define DHH   16
#define NEDGE 65536
#define FFN   512
#define EPSV  1e-5f
#define CAP   256
#define NBLK  256
#define NTHR  512

struct Params {
    const float *node, *edge_feat;
    const int *src, *dst;
    const float *Wq, *bq, *Wk, *bk, *Wv, *bv, *Wo, *bo, *We, *be;
    const float *g1, *b1n, *g2n, *b2n, *W1, *bf1, *W2, *bf2;
    float *Qf, *Kf, *Vf, *out;
    int* eid;
    unsigned* bm;
    float* eb;
};

union Smem {
    struct { float sx[8][DDIM]; float rq[4][8][DDIM]; float rk[4][8][DDIM];
             float rv[4][8][DDIM]; } q;                                       // 52 KB
    struct { float qrow[2][DDIM]; int lj[2][CAP + 8]; int lev[2][CAP + 8];
             float sc[2][CAP + 8][HH]; float hinv[2][HH];
             float redpv[2][2][DDIM]; int scnt[2]; } a;                       // ~24 KB
    struct { float red[4][8][DDIM]; float x1[8][DDIM]; float sh[8][FFN];
             float4 sc4[8]; } tl;                                             // ~36 KB
};
struct Pers { float ao[8][DDIM]; };                                           // 4 KB

__device__ __forceinline__ bool idx64(const int* src) {
    return (src[1] | src[3] | src[5] | src[7] | src[9] | src[11]) == 0;
}

// ===== phase 1: prep (bm clear, eid=-2 cells, edge bias) + QKV rows 8b..8b+7 =====
__device__ __forceinline__ void phase_pq(const Params& P, int b, int t, Smem& S, bool is64) {
    int g = b * NTHR + t;
    if (g < NN * 64 / 4) ((int4*)P.bm)[g] = make_int4(0, 0, 0, 0);
    if (g < NN) P.eid[(long)g * NN + g] = -2;
    if (g < NEDGE) {
        int s = is64 ? P.src[2 * g] : P.src[g];
        int d = is64 ? P.dst[2 * g] : P.dst[g];
        P.eid[(long)s * NN + d] = -2;
        P.eid[(long)d * NN + s] = -2;
        float ef[10];
#pragma unroll
        for (int k = 0; k < 10; k++) ef[k] = P.edge_feat[g * 10 + k];
#pragma unroll
        for (int h = 0; h < 8; h++) {
            float a = P.be[h];
#pragma unroll
            for (int k = 0; k < 10; k++) a += ef[k] * P.We[k * 8 + h];
            P.eb[g * 8 + h] = a;
        }
    }
    int r0 = b * 8, c = t & 127, ks = t >> 7;
    S.q.sx[ks][c]     = P.node[r0 * DDIM + t];
    S.q.sx[4 + ks][c] = P.node[r0 * DDIM + 512 + t];
    __syncthreads();
    float aq[8], ak[8], av[8];
#pragma unroll
    for (int r = 0; r < 8; r++) { aq[r] = 0; ak[r] = 0; av[r] = 0; }
    int kbeg = ks * 32;
#pragma unroll 8
    for (int k = kbeg; k < kbeg + 32; k++) {
        float wq = P.Wq[k * DDIM + c];
        float wk = P.Wk[k * DDIM + c];
        float wv = P.Wv[k * DDIM + c];
#pragma unroll
        for (int r = 0; r < 8; r++) {
            float xv = S.q.sx[r][k];
            aq[r] += xv * wq; ak[r] += xv * wk; av[r] += xv * wv;
        }
    }
#pragma unroll
    for (int r = 0; r < 8; r++) {
        S.q.rq[ks][r][c] = aq[r];
        S.q.rk[ks][r][c] = ak[r];
        S.q.rv[ks][r][c] = av[r];
    }
    __syncthreads();
    int rr = t >> 7, cc = t & 127;
    float vq0 = 0, vk0 = 0, vv0 = 0, vq1 = 0, vk1 = 0, vv1 = 0;
#pragma unroll
    for (int s = 0; s < 4; s++) {
        vq0 += S.q.rq[s][rr][cc];     vk0 += S.q.rk[s][rr][cc];     vv0 += S.q.rv[s][rr][cc];
        vq1 += S.q.rq[s][rr + 4][cc]; vk1 += S.q.rk[s][rr + 4][cc]; vv1 += S.q.rv[s][rr + 4][cc];
    }
    float vbq = P.bq[cc], vbk = P.bk[cc], vbv = P.bv[cc];
    P.Qf[(r0 + rr) * DDIM + cc]     = (vq0 + vbq) * 0.25f;
    P.Kf[(r0 + rr) * DDIM + cc]     = vk0 + vbk;
    P.Vf[(r0 + rr) * DDIM + cc]     = vv0 + vbv;
    P.Qf[(r0 + rr + 4) * DDIM + cc] = (vq1 + vbq) * 0.25f;
    P.Kf[(r0 + rr + 4) * DDIM + cc] = vk1 + vbk;
    P.Vf[(r0 + rr + 4) * DDIM + cc] = vv1 + vbv;
}

// ===== phase 2: scatter (bitmap OR + eid max = last-wins) =====
__device__ __forceinline__ void phase_scatter(const Params& P, int b, int t, bool is64) {
    int g = b * NTHR + t;
    if (g < NEDGE) {
        int s = is64 ? P.src[2 * g] : P.src[g];
        int d = is64 ? P.dst[2 * g] : P.dst[g];
        atomicOr(&P.bm[s * 64 + (d >> 5)], 1u << (d & 31));
        atomicOr(&P.bm[d * 64 + (s >> 5)], 1u << (s & 31));
        atomicMax(&P.eid[(long)s * NN + d], g);
    } else if (g < NEDGE + NN) {
        int i = g - NEDGE;
        atomicOr(&P.bm[i * 64 + (i >> 5)], 1u << (i & 31));
    }
}

// ===== phase 3: attention, rows 8b..8b+7 as 4 passes x (2 rows x 256 thr) =====
__device__ __forceinline__ void phase_attn(const Params& P, int b, int t, Smem& S, Pers& Pr) {
    int gi = t >> 8;
    int t2 = t & 255;
#pragma unroll 1
    for (int p = 0; p < 4; p++) {
        __syncthreads();
        int il = p * 2 + gi;
        int i = b * 8 + il;
        if (t2 < 128) S.a.qrow[gi][t2] = P.Qf[i * DDIM + t2];
        if (t2 < 64) {
            unsigned word = P.bm[i * 64 + t2];
            int pc = __popc(word);
            int x = pc;
#pragma unroll
            for (int off = 1; off < 64; off <<= 1) {
                int y = __shfl_up(x, off);
                if (t2 >= off) x += y;
            }
            int cnt = __shfl(x, 63);
            if (cnt > CAP - 8) cnt = CAP - 8;
            int idx = x - pc;
            unsigned w = word;
            while (w && idx < CAP) {
                int bp = __ffs(w) - 1;
                S.a.lj[gi][idx++] = (t2 << 5) + bp;
                w &= w - 1;
            }
            if (t2 < 8) S.a.lj[gi][cnt + t2] = 0;
            if (t2 == 0) S.a.scnt[gi] = cnt;
        }
        __syncthreads();
        int cnt = S.a.scnt[gi];
        int cnt8 = (cnt + 7) & ~7;
        if (t2 < cnt8)
            S.a.lev[gi][t2] = (t2 < cnt) ? P.eid[(long)i * NN + S.a.lj[gi][t2]] : -1;
        __syncthreads();
        // scores: 32 slots x 8 heads
        {
            int h = t2 & 7, nsl = t2 >> 3;
            const float4* q4 = (const float4*)(&S.a.qrow[gi][h * DHH]);
            float4 q0 = q4[0], q1 = q4[1], q2 = q4[2], q3 = q4[3];
            for (int n = nsl; n < cnt8; n += 32) {
                int j = S.a.lj[gi][n];
                const float4* k4 = (const float4*)(P.Kf + j * DDIM + h * DHH);
                float4 k0 = k4[0], k1 = k4[1], k2 = k4[2], k3 = k4[3];
                float s = q0.x * k0.x + q0.y * k0.y + q0.z * k0.z + q0.w * k0.w
                        + q1.x * k1.x + q1.y * k1.y + q1.z * k1.z + q1.w * k1.w
                        + q2.x * k2.x + q2.y * k2.y + q2.z * k2.z + q2.w * k2.w
                        + q3.x * k3.x + q3.y * k3.y + q3.z * k3.z + q3.w * k3.w;
                int ev = S.a.lev[gi][n];
                if (ev >= 0) s += P.eb[ev * 8 + h];
                S.a.sc[gi][n][h] = s;
            }
        }
        __syncthreads();
        // softmax: 32 threads per head
        {
            int hh = t2 >> 5, sub = t2 & 31;
            float m = -1e30f;
            for (int n = sub; n < cnt; n += 32) m = fmaxf(m, S.a.sc[gi][n][hh]);
#pragma unroll
            for (int off = 1; off < 32; off <<= 1) m = fmaxf(m, __shfl_xor(m, off));
            float ssum = 0.f;
            for (int n = sub; n < cnt; n += 32) {
                float e = __expf(S.a.sc[gi][n][hh] - m);
                S.a.sc[gi][n][hh] = e;
                ssum += e;
            }
#pragma unroll
            for (int off = 1; off < 32; off <<= 1) ssum += __shfl_xor(ssum, off);
            if (sub == 0) S.a.hinv[gi][hh] = 1.0f / ssum;
        }
        if (t2 < 64) {
            int pp = cnt + (t2 >> 3);
            if (pp < cnt8) S.a.sc[gi][pp][t2 & 7] = 0.f;
        }
        __syncthreads();
        // PV: 2 groups of 128 threads
        {
            int gg = t2 >> 7, c = t2 & 127, h2 = c >> 4;
            float a = 0.f;
#pragma unroll 4
            for (int n = gg; n < cnt8; n += 2)
                a += S.a.sc[gi][n][h2] * P.Vf[S.a.lj[gi][n] * DDIM + c];
            S.a.redpv[gi][gg][c] = a;
        }
        __syncthreads();
        if (t2 < 128)
            Pr.ao[il][t2] = (S.a.redpv[gi][0][t2] + S.a.redpv[gi][1][t2]) * S.a.hinv[gi][t2 >> 4];
    }
}

// ===== phase 4: tail — Wo+LN1 -> FFN1 -> FFN2+LN2, rows 8b..8b+7 =====
__device__ __forceinline__ void phase_tail(const Params& P, int b, int t, Smem& S, Pers& Pr) {
    int r0 = b * 8, c = t & 127, ks = t >> 7;
    int rr = t >> 7, cc = t & 127;
    // A: Wo proj + bias + residual + LN1 -> x1
    {
        float acc[8] = {0, 0, 0, 0, 0, 0, 0, 0};
        int kbeg = ks * 32;
#pragma unroll 8
        for (int k = kbeg; k < kbeg + 32; k++) {
            float w = P.Wo[k * DDIM + c];
#pragma unroll
            for (int r = 0; r < 8; r++) acc[r] += Pr.ao[r][k] * w;
        }
#pragma unroll
        for (int r = 0; r < 8; r++) S.tl.red[ks][r][c] = acc[r];
        __syncthreads();
        float bov = P.bo[cc];
        float val0 = S.tl.red[0][rr][cc] + S.tl.red[1][rr][cc] + S.tl.red[2][rr][cc]
                   + S.tl.red[3][rr][cc] + bov + P.node[(r0 + rr) * DDIM + cc];
        float val1 = S.tl.red[0][rr + 4][cc] + S.tl.red[1][rr + 4][cc] + S.tl.red[2][rr + 4][cc]
                   + S.tl.red[3][rr + 4][cc] + bov + P.node[(r0 + rr + 4) * DDIM + cc];
        float4 v = make_float4(val0, val0 * val0, val1, val1 * val1);
#pragma unroll
        for (int off = 32; off >= 1; off >>= 1) {
            v.x += __shfl_down(v.x, off);
            v.y += __shfl_down(v.y, off);
            v.z += __shfl_down(v.z, off);
            v.w += __shfl_down(v.w, off);
        }
        if ((t & 63) == 0) S.tl.sc4[t >> 6] = v;
        __syncthreads();
        float gv = P.g1[cc], bv = P.b1n[cc];
        {
            float sum = S.tl.sc4[2 * rr].x + S.tl.sc4[2 * rr + 1].x;
            float sq  = S.tl.sc4[2 * rr].y + S.tl.sc4[2 * rr + 1].y;
            float mu = sum * (1.0f / DDIM);
            float var = sq * (1.0f / DDIM) - mu * mu;
            S.tl.x1[rr][cc] = (val0 - mu) * rsqrtf(var + EPSV) * gv + bv;
        }
        {
            float sum = S.tl.sc4[2 * rr].z + S.tl.sc4[2 * rr + 1].z;
            float sq  = S.tl.sc4[2 * rr].w + S.tl.sc4[2 * rr + 1].w;
            float mu = sum * (1.0f / DDIM);
            float var = sq * (1.0f / DDIM) - mu * mu;
            S.tl.x1[rr + 4][cc] = (val1 - mu) * rsqrtf(var + EPSV) * gv + bv;
        }
    }
    __syncthreads();
    // B: hidden = relu(x1 @ W1 + bf1), column t of 512
    {
        float acc[8] = {0, 0, 0, 0, 0, 0, 0, 0};
#pragma unroll 4
        for (int k = 0; k < DDIM; k++) {
            float w = P.W1[k * FFN + t];
#pragma unroll
            for (int r = 0; r < 8; r++) acc[r] += S.tl.x1[r][k] * w;
        }
        float bb = P.bf1[t];
#pragma unroll
        for (int r = 0; r < 8; r++) S.tl.sh[r][t] = fmaxf(acc[r] + bb, 0.f);
    }
    __syncthreads();
    // C: ffn2 + bias + residual + LN2 -> out
    {
        float acc[8] = {0, 0, 0, 0, 0, 0, 0, 0};
        int kbeg = ks * 128;
#pragma unroll 8
        for (int k = kbeg; k < kbeg + 128; k++) {
            float w = P.W2[k * DDIM + c];
#pragma unroll
            for (int r = 0; r < 8; r++) acc[r] += S.tl.sh[r][k] * w;
        }
        __syncthreads();  // x1 reads done? No: x1 still needed below; red overlaps x1? red and x1 are distinct members of tl ✓ sync guards red reuse from phase A reads
#pragma unroll
        for (int r = 0; r < 8; r++) S.tl.red[ks][r][c] = acc[r];
        __syncthreads();
        float bv2 = P.bf2[cc];
        float val0 = S.tl.red[0][rr][cc] + S.tl.red[1][rr][cc] + S.tl.red[2][rr][cc]
                   + S.tl.red[3][rr][cc] + bv2 + S.tl.x1[rr][cc];
        float val1 = S.tl.red[0][rr + 4][cc] + S.tl.red[1][rr + 4][cc] + S.tl.red[2][rr + 4][cc]
                   + S.tl.red[3][rr + 4][cc] + bv2 + S.tl.x1[rr + 4][cc];
        float4 v = make_float4(val0, val0 * val0, val1, val1 * val1);
#pragma unroll
        for (int off = 32; off >= 1; off >>= 1) {
            v.x += __shfl_down(v.x, off);
            v.y += __shfl_down(v.y, off);
            v.z += __shfl_down(v.z, off);
            v.w += __shfl_down(v.w, off);
        }
        if ((t & 63) == 0) S.tl.sc4[t >> 6] = v;
        __syncthreads();
        float gv = P.g2n[cc], bv = P.b2n[cc];
        {
            float sum = S.tl.sc4[2 * rr].x + S.tl.sc4[2 * rr + 1].x;
            float sq  = S.tl.sc4[2 * rr].y + S.tl.sc4[2 * rr + 1].y;
            float mu = sum * (1.0f / DDIM);
            float var = sq * (1.0f / DDIM) - mu * mu;
            P.out[(r0 + rr) * DDIM + cc] = (val0 - mu) * rsqrtf(var + EPSV) * gv + bv;
        }
        {
            float sum = S.tl.sc4[2 * rr].z + S.tl.sc4[2 * rr + 1].z;
            float sq  = S.tl.sc4[2 * rr].w + S.tl.sc4[2 * rr + 1].w;
            float mu = sum * (1.0f / DDIM);
            float var = sq * (1.0f / DDIM) - mu * mu;
            P.out[(r0 + rr + 4) * DDIM + cc] = (val1 - mu) * rsqrtf(var + EPSV) * gv + bv;
        }
    }
}

// ===== cooperative mega-kernel =====
__global__ __launch_bounds__(NTHR, 2) void k_mega(Params P) {
    __shared__ Smem S;
    __shared__ Pers Pr;
    int b = blockIdx.x, t = threadIdx.x;
    bool is64 = idx64(P.src);
    phase_pq(P, b, t, S, is64);
    cg::this_grid().sync();
    phase_scatter(P, b, t, is64);
    cg::this_grid().sync();
    phase_attn(P, b, t, S, Pr);
    __syncthreads();
    phase_tail(P, b, t, S, Pr);
}

// ===== fallback: same phases as 3 plain kernels =====
__global__ __launch_bounds__(NTHR, 2) void k_f1(Params P) {
    __shared__ Smem S;
    phase_pq(P, blockIdx.x, threadIdx.x, S, idx64(P.src));
}
__global__ __launch_bounds__(NTHR, 2) void k_f2(Params P) {
    phase_scatter(P, blockIdx.x, threadIdx.x, idx64(P.src));
}
__global__ __launch_bounds__(NTHR, 2) void k_f3(Params P) {
    __shared__ Smem S;
    __shared__ Pers Pr;
    phase_attn(P, blockIdx.x, threadIdx.x, S, Pr);
    __syncthreads();
    phase_tail(P, blockIdx.x, threadIdx.x, S, Pr);
}

extern "C" void kernel_launch(void* const* d_in, const int* in_sizes, int n_in,
                              void* d_out, int out_size, void* d_ws, size_t ws_size,
                              hipStream_t stream) {
    Params P;
    P.node      = (const float*)d_in[0];
    P.edge_feat = (const float*)d_in[1];
    P.src = (const int*)d_in[2];
    P.dst = (const int*)d_in[3];
    P.Wq = (const float*)d_in[4];   P.bq = (const float*)d_in[5];
    P.Wk = (const float*)d_in[6];   P.bk = (const float*)d_in[7];
    P.Wv = (const float*)d_in[8];   P.bv = (const float*)d_in[9];
    P.Wo = (const float*)d_in[10];  P.bo = (const float*)d_in[11];
    P.We = (const float*)d_in[12];  P.be = (const float*)d_in[13];
    P.g1 = (const float*)d_in[14];  P.b1n = (const float*)d_in[15];
    P.g2n = (const float*)d_in[16]; P.b2n = (const float*)d_in[17];
    P.W1 = (const float*)d_in[18];  P.bf1 = (const float*)d_in[19];
    P.W2 = (const float*)d_in[20];  P.bf2 = (const float*)d_in[21];

    char* ws = (char*)d_ws;
    P.eid = (int*)ws;      ws += (size_t)NN * NN * 4;     // 16.8 MB
    P.bm  = (unsigned*)ws; ws += (size_t)NN * 64 * 4;     // 512 KB
    P.eb  = (float*)ws;    ws += (size_t)NEDGE * 8 * 4;   // 2 MB
    P.Qf  = (float*)ws;    ws += (size_t)NN * DDIM * 4;
    P.Kf  = (float*)ws;    ws += (size_t)NN * DDIM * 4;
    P.Vf  = (float*)ws;    ws += (size_t)NN * DDIM * 4;
    P.out = (float*)d_out;

    int dev = 0;
    hipGetDevice(&dev);
    int coop = 0;
    hipDeviceGetAttribute(&coop, hipDeviceAttributeCooperativeLaunch, dev);

    bool done = false;
    if (coop) {
        void* args[] = { &P };
        hipError_t e = hipLaunchCooperativeKernel(reinterpret_cast<void*>(k_mega),
                                                  dim3(NBLK), dim3(NTHR), args, 0, stream);
        done = (e == hipSuccess);
    }
    if (!done) {
        k_f1<<<NBLK, NTHR, 0, stream>>>(P);
        k_f2<<<NBLK, NTHR, 0, stream>>>(P);
        k_f3<<<NBLK, NTHR, 0, stream>>>(P);
    }
}

// Round 10
// 75.626 us; speedup vs baseline: 1.9125x; 1.9125x over previous
//
#include <hip/hip_runtime.h>
#include <hip/hip_bf16.h>

#define NN   2048
#define DDIM 128
#define HH    8
#define DHH  16
#define NEDGE 65536
#define FFN  512
#define EPSV 1e-5f
#define CAP  256

typedef const float* fp_c;

// int64 vs int32 index layout: int64 values < 2048 have all-zero odd words.
__device__ __forceinline__ bool idx64(const int* src) {
    return (src[1] | src[3] | src[5] | src[7] | src[9] | src[11]) == 0;
}

// ================= fused prep + QKV =================
// blocks 0..511: QKV GEMM rows 4b..4b+3 (ROWS=4, 26KB LDS -> 2 blocks/CU).
// blocks 512..767: prep (clear bm 512KB + ewin 2MB, edge-bias mini-GEMM).
__global__ __launch_bounds__(512) void k_pq(float* Qf, float* Kf, float* Vf, fp_c x,
                                            fp_c Wq, fp_c bq, fp_c Wk, fp_c bk, fp_c Wv, fp_c bv,
                                            int* ewin, unsigned* bm, float* eb,
                                            const int* src, const int* dst,
                                            fp_c edge_feat, fp_c We, fp_c be) {
    int b = blockIdx.x;
    int t = threadIdx.x;
    if (b < 512) {
        __shared__ float sx[4][DDIM];
        __shared__ float red[3][4][4][DDIM];
        int r0 = b * 4;
        int c = t & 127;
        int ks = t >> 7;
        sx[ks][c] = x[r0 * DDIM + t];
        __syncthreads();
        float aq[4] = {0, 0, 0, 0}, ak[4] = {0, 0, 0, 0}, av[4] = {0, 0, 0, 0};
        int kbeg = ks * 32;
#pragma unroll 8
        for (int k = kbeg; k < kbeg + 32; k++) {
            float wq = Wq[k * DDIM + c];
            float wk = Wk[k * DDIM + c];
            float wv = Wv[k * DDIM + c];
#pragma unroll
            for (int r = 0; r < 4; r++) {
                float xv = sx[r][k];
                aq[r] += xv * wq; ak[r] += xv * wk; av[r] += xv * wv;
            }
        }
#pragma unroll
        for (int r = 0; r < 4; r++) {
            red[0][ks][r][c] = aq[r];
            red[1][ks][r][c] = ak[r];
            red[2][ks][r][c] = av[r];
        }
        __syncthreads();
        int rr = t >> 7, cc = t & 127;
        float vq = 0, vk = 0, vv = 0;
#pragma unroll
        for (int s = 0; s < 4; s++) {
            vq += red[0][s][rr][cc];
            vk += red[1][s][rr][cc];
            vv += red[2][s][rr][cc];
        }
        Qf[(r0 + rr) * DDIM + cc] = (vq + bq[cc]) * 0.25f;
        Kf[(r0 + rr) * DDIM + cc] = vk + bk[cc];
        Vf[(r0 + rr) * DDIM + cc] = vv + bv[cc];
    } else {
        __shared__ float sWe[80];
        __shared__ float sbe[8];
        if (t < 80) sWe[t] = We[t];
        if (t < 8)  sbe[t] = be[t];
        __syncthreads();
        int u = (b - 512) * 512 + t;   // 0..131071
        if (u < NN * 64 / 4) ((int4*)bm)[u] = make_int4(0, 0, 0, 0);
        ((int4*)ewin)[u] = make_int4(0, 0, 0, 0);   // NN*CAP/4 = 131072 exactly
        if (u < NEDGE) {
            float ef[10];
#pragma unroll
            for (int k = 0; k < 10; k++) ef[k] = edge_feat[u * 10 + k];
#pragma unroll
            for (int h = 0; h < 8; h++) {
                float a = sbe[h];
#pragma unroll
                for (int k = 0; k < 10; k++) a += ef[k] * sWe[k * 8 + h];
                eb[u * 8 + h] = a;
            }
        }
    }
}

// ---------------- scatter: adjacency bitmap ----------------
__global__ __launch_bounds__(512) void k_scatter(unsigned* bm, const int* src, const int* dst) {
    int t = blockIdx.x * blockDim.x + threadIdx.x;
    bool is64 = idx64(src);
    if (t < NEDGE) {
        int s = is64 ? src[2 * t] : src[t];
        int d = is64 ? dst[2 * t] : dst[t];
        atomicOr(&bm[s * 64 + (d >> 5)], 1u << (d & 31));
        atomicOr(&bm[d * 64 + (s >> 5)], 1u << (s & 31));
    } else if (t < NEDGE + NN) {
        int i = t - NEDGE;
        atomicOr(&bm[i * 64 + (i >> 5)], 1u << (i & 31));
    }
}

// ---------------- rank: edge -> rank slot in its row, max(e+1) = last-wins ----------------
__global__ __launch_bounds__(256) void k_rank(int* ewin, const unsigned* bm,
                                              const int* src, const int* dst) {
    int e = blockIdx.x * 256 + threadIdx.x;
    if (e >= NEDGE) return;
    bool is64 = idx64(src);
    int s = is64 ? src[2 * e] : src[e];
    int d = is64 ? dst[2 * e] : dst[e];
    const int4* row4 = (const int4*)(bm + s * 64);
    int dw = d >> 5;          // word 0..63
    int dq = dw >> 2;         // int4 idx 0..15
    int rank = 0;
#pragma unroll 4
    for (int q = 0; q < dq; q++) {
        int4 w = row4[q];
        rank += __popc((unsigned)w.x) + __popc((unsigned)w.y)
              + __popc((unsigned)w.z) + __popc((unsigned)w.w);
    }
    int4 wl = row4[dq];
    unsigned wz[4] = {(unsigned)wl.x, (unsigned)wl.y, (unsigned)wl.z, (unsigned)wl.w};
    int rem = dw & 3;
#pragma unroll
    for (int k = 0; k < 3; k++) if (k < rem) rank += __popc(wz[k]);
    rank += __popc(wz[rem] & ((1u << (d & 31)) - 1u));
    atomicMax(&ewin[s * CAP + rank], e + 1);
}

// ---------------- sparse masked attention: 256 threads (4 waves) per row ----------------
__global__ __launch_bounds__(256) void k_attn(float* attn_out, const float* Qf, const float* Kf,
                                              const float* Vf, const int* ewin, const float* eb,
                                              const unsigned* bm) {
    __shared__ float qrow[DDIM];
    __shared__ int   lj[CAP + 8];
    __shared__ int   lev[CAP + 8];
    __shared__ float sc[CAP + 8][HH];
    __shared__ float hinv[HH];
    __shared__ float redpv[2][DDIM];
    __shared__ int   scnt;
    int i = blockIdx.x;
    int t = threadIdx.x;
    if (t < 128) qrow[t] = Qf[i * DDIM + t];

    // phase 1 (wave 0): bitmap -> compacted neighbor list (ascending j)
    if (t < 64) {
        unsigned word = bm[i * 64 + t];
        int pc = __popc(word);
        int x = pc;
#pragma unroll
        for (int off = 1; off < 64; off <<= 1) {
            int y = __shfl_up(x, off);
            if (t >= off) x += y;
        }
        int cnt = __shfl(x, 63);
        if (cnt > CAP - 8) cnt = CAP - 8;
        int idx = x - pc;
        unsigned w = word;
        while (w && idx < CAP) {
            int bp = __ffs(w) - 1;
            lj[idx++] = (t << 5) + bp;
            w &= w - 1;
        }
        if (t < 8) lj[cnt + t] = 0;  // pad
        if (t == 0) scnt = cnt;
    }
    __syncthreads();
    int cnt = scnt;
    int cnt8 = (cnt + 7) & ~7;
    // rank-indexed bias id: contiguous, coalesced read
    if (t < cnt8) lev[t] = (t < cnt) ? (ewin[i * CAP + t] - 1) : -1;
    __syncthreads();

    // phase 2: scores — 32 neighbor slots x 8 heads in parallel
    int h = t & 7;
    int nsl = t >> 3;
    const float4* q4 = (const float4*)(qrow + h * DHH);
    float4 q0 = q4[0], q1 = q4[1], q2 = q4[2], q3 = q4[3];
    for (int n = nsl; n < cnt8; n += 32) {
        int j = lj[n];
        const float4* k4 = (const float4*)(Kf + j * DDIM + h * DHH);
        float4 k0 = k4[0], k1 = k4[1], k2 = k4[2], k3 = k4[3];
        float s = q0.x * k0.x + q0.y * k0.y + q0.z * k0.z + q0.w * k0.w
                + q1.x * k1.x + q1.y * k1.y + q1.z * k1.z + q1.w * k1.w
                + q2.x * k2.x + q2.y * k2.y + q2.z * k2.z + q2.w * k2.w
                + q3.x * k3.x + q3.y * k3.y + q3.z * k3.z + q3.w * k3.w;
        int ev = lev[n];
        if (ev >= 0) s += eb[ev * 8 + h];
        sc[n][h] = s;
    }
    __syncthreads();

    // phase 3: per-head softmax — 32 threads per head
    {
        int hh = t >> 5, sub = t & 31;
        float m = -1e30f;
        for (int n = sub; n < cnt; n += 32) m = fmaxf(m, sc[n][hh]);
#pragma unroll
        for (int off = 1; off < 32; off <<= 1) m = fmaxf(m, __shfl_xor(m, off));
        float ssum = 0.f;
        for (int n = sub; n < cnt; n += 32) {
            float e = __expf(sc[n][hh] - m);
            sc[n][hh] = e;
            ssum += e;
        }
#pragma unroll
        for (int off = 1; off < 32; off <<= 1) ssum += __shfl_xor(ssum, off);
        if (sub == 0) hinv[hh] = 1.0f / ssum;
    }
    // zero pad rows
    if (t < 64) {
        int p = cnt + (t >> 3);
        if (p < cnt8) sc[p][t & 7] = 0.f;
    }
    __syncthreads();

    // phase 4: PV — neighbors split across 2 groups of 128 threads
    {
        int g = t >> 7, c = t & 127, h2 = c >> 4;
        float a = 0.f;
#pragma unroll 4
        for (int n = g; n < cnt8; n += 2)
            a += sc[n][h2] * Vf[lj[n] * DDIM + c];
        redpv[g][c] = a;
    }
    __syncthreads();
    if (t < 128)
        attn_out[i * DDIM + t] = (redpv[0][t] + redpv[1][t]) * hinv[t >> 4];
}

// ================= fused tail: Wo+LN1 -> FFN1 -> FFN2+LN2, ROWS=4 =================
__global__ __launch_bounds__(512) void k_tail(float* out, const float* ain,
                                              fp_c Wo, fp_c bo, fp_c node, fp_c g1, fp_c b1,
                                              fp_c W1, fp_c bf1, fp_c W2, fp_c bf2,
                                              fp_c g2, fp_c b2) {
    __shared__ float sa[4][DDIM];
    __shared__ float red[4][4][DDIM];
    __shared__ float x1ld[4][DDIM];
    __shared__ float sh[4][FFN];
    __shared__ float2 sc2[8];
    int t = threadIdx.x;
    int r0 = blockIdx.x * 4;
    int c = t & 127;
    int ks = t >> 7;
    int rr = t >> 7, cc = t & 127;
    sa[rr][cc] = ain[r0 * DDIM + t];
    __syncthreads();

    // phase A: Wo proj (K-split 4) + bias + residual + LN1 -> x1ld
    {
        float acc[4] = {0, 0, 0, 0};
        int kbeg = ks * 32;
#pragma unroll 8
        for (int k = kbeg; k < kbeg + 32; k++) {
            float w = Wo[k * DDIM + c];
#pragma unroll
            for (int r = 0; r < 4; r++) acc[r] += sa[r][k] * w;
        }
#pragma unroll
        for (int r = 0; r < 4; r++) red[ks][r][c] = acc[r];
        __syncthreads();
        float val = red[0][rr][cc] + red[1][rr][cc] + red[2][rr][cc] + red[3][rr][cc];
        val += bo[cc] + node[(r0 + rr) * DDIM + cc];
        float vs = val, vq = val * val;
#pragma unroll
        for (int off = 32; off >= 1; off >>= 1) {
            vs += __shfl_down(vs, off);
            vq += __shfl_down(vq, off);
        }
        if ((t & 63) == 0) sc2[t >> 6] = make_float2(vs, vq);
        __syncthreads();
        float sum = sc2[2 * rr].x + sc2[2 * rr + 1].x;
        float sq  = sc2[2 * rr].y + sc2[2 * rr + 1].y;
        float mu = sum * (1.0f / DDIM);
        float var = sq * (1.0f / DDIM) - mu * mu;
        x1ld[rr][cc] = (val - mu) * rsqrtf(var + EPSV) * g1[cc] + b1[cc];
    }
    __syncthreads();

    // phase B: hidden = relu(x1 @ W1 + bf1), column t of 512
    {
        float acc[4] = {0, 0, 0, 0};
#pragma unroll 8
        for (int k = 0; k < DDIM; k++) {
            float w = W1[k * FFN + t];
#pragma unroll
            for (int r = 0; r < 4; r++) acc[r] += x1ld[r][k] * w;
        }
        float bb = bf1[t];
#pragma unroll
        for (int r = 0; r < 4; r++) sh[r][t] = fmaxf(acc[r] + bb, 0.f);
    }
    __syncthreads();

    // phase C: ffn2 (K-split 4 over 512) + bias + residual + LN2 -> out
    {
        float acc[4] = {0, 0, 0, 0};
        int kbeg = ks * 128;
#pragma unroll 8
        for (int k = kbeg; k < kbeg + 128; k++) {
            float w = W2[k * DDIM + c];
#pragma unroll
            for (int r = 0; r < 4; r++) acc[r] += sh[r][k] * w;
        }
#pragma unroll
        for (int r = 0; r < 4; r++) red[ks][r][c] = acc[r];
        __syncthreads();
        float val = red[0][rr][cc] + red[1][rr][cc] + red[2][rr][cc] + red[3][rr][cc];
        val += bf2[cc] + x1ld[rr][cc];
        float vs = val, vq = val * val;
#pragma unroll
        for (int off = 32; off >= 1; off >>= 1) {
            vs += __shfl_down(vs, off);
            vq += __shfl_down(vq, off);
        }
        if ((t & 63) == 0) sc2[t >> 6] = make_float2(vs, vq);
        __syncthreads();
        float sum = sc2[2 * rr].x + sc2[2 * rr + 1].x;
        float sq  = sc2[2 * rr].y + sc2[2 * rr + 1].y;
        float mu = sum * (1.0f / DDIM);
        float var = sq * (1.0f / DDIM) - mu * mu;
        out[(r0 + rr) * DDIM + cc] = (val - mu) * rsqrtf(var + EPSV) * g2[cc] + b2[cc];
    }
}

extern "C" void kernel_launch(void* const* d_in, const int* in_sizes, int n_in,
                              void* d_out, int out_size, void* d_ws, size_t ws_size,
                              hipStream_t stream) {
    fp_c node = (fp_c)d_in[0];
    fp_c edge_feat = (fp_c)d_in[1];
    const int* src = (const int*)d_in[2];
    const int* dst = (const int*)d_in[3];
    fp_c Wq = (fp_c)d_in[4];  fp_c bq = (fp_c)d_in[5];
    fp_c Wk = (fp_c)d_in[6];  fp_c bk = (fp_c)d_in[7];
    fp_c Wv = (fp_c)d_in[8];  fp_c bv = (fp_c)d_in[9];
    fp_c Wo = (fp_c)d_in[10]; fp_c bo = (fp_c)d_in[11];
    fp_c We = (fp_c)d_in[12]; fp_c be = (fp_c)d_in[13];
    fp_c g1 = (fp_c)d_in[14]; fp_c b1n = (fp_c)d_in[15];
    fp_c g2 = (fp_c)d_in[16]; fp_c b2n = (fp_c)d_in[17];
    fp_c W1 = (fp_c)d_in[18]; fp_c bf1 = (fp_c)d_in[19];
    fp_c W2 = (fp_c)d_in[20]; fp_c bf2 = (fp_c)d_in[21];

    char* ws = (char*)d_ws;
    int* ewin     = (int*)ws;      ws += (size_t)NN * CAP * 4;   // 2 MB
    unsigned* bm  = (unsigned*)ws; ws += (size_t)NN * 64 * 4;    // 512 KB
    float* eb     = (float*)ws;    ws += (size_t)NEDGE * 8 * 4;  // 2 MB
    float* Qf     = (float*)ws;    ws += (size_t)NN * DDIM * 4;  // 1 MB
    float* Kf     = (float*)ws;    ws += (size_t)NN * DDIM * 4;  // 1 MB
    float* Vf     = (float*)ws;    ws += (size_t)NN * DDIM * 4;  // 1 MB
    float* attn_o = (float*)ws;    ws += (size_t)NN * DDIM * 4;  // 1 MB

    k_pq<<<768, 512, 0, stream>>>(Qf, Kf, Vf, node, Wq, bq, Wk, bk, Wv, bv,
                                  ewin, bm, eb, src, dst, edge_feat, We, be);
    k_scatter<<<(NEDGE + NN + 511) / 512, 512, 0, stream>>>(bm, src, dst);
    k_rank<<<NEDGE / 256, 256, 0, stream>>>(ewin, bm, src, dst);
    k_attn<<<NN, 256, 0, stream>>>(attn_o, Qf, Kf, Vf, ewin, eb, bm);
    k_tail<<<NN / 4, 512, 0, stream>>>((float*)d_out, attn_o, Wo, bo, node, g1, b1n,
                                       W1, bf1, W2, bf2, g2, b2n);
}

// Round 11
// 71.422 us; speedup vs baseline: 2.0250x; 1.0589x over previous
//
#include <hip/hip_runtime.h>
#include <hip/hip_bf16.h>

#define NN   2048
#define DDIM 128
#define HH    8
#define DHH  16
#define NEDGE 65536
#define FFN  512
#define EPSV 1e-5f
#define CAP  256

typedef const float* fp_c;

// int64 vs int32 index layout: int64 values < 2048 have all-zero odd words.
__device__ __forceinline__ bool idx64(const int* src) {
    return (src[1] | src[3] | src[5] | src[7] | src[9] | src[11]) == 0;
}

// ================= L1: fused prep + QKV (R5-proven) =================
// blocks 0..511: QKV GEMM rows 4b..4b+3. blocks 512..767: prep.
__global__ __launch_bounds__(512) void k_pq(float* Qf, float* Kf, float* Vf, fp_c x,
                                            fp_c Wq, fp_c bq, fp_c Wk, fp_c bk, fp_c Wv, fp_c bv,
                                            int* eid, unsigned* bm, float* eb,
                                            const int* src, const int* dst,
                                            fp_c edge_feat, fp_c We, fp_c be) {
    int b = blockIdx.x;
    int t = threadIdx.x;
    if (b < 512) {
        __shared__ float sx[4][DDIM];
        __shared__ float red[3][4][4][DDIM];
        int r0 = b * 4;
        int c = t & 127;
        int ks = t >> 7;
        sx[ks][c] = x[r0 * DDIM + t];
        __syncthreads();
        float aq[4] = {0, 0, 0, 0}, ak[4] = {0, 0, 0, 0}, av[4] = {0, 0, 0, 0};
        int kbeg = ks * 32;
#pragma unroll 8
        for (int k = kbeg; k < kbeg + 32; k++) {
            float wq = Wq[k * DDIM + c];
            float wk = Wk[k * DDIM + c];
            float wv = Wv[k * DDIM + c];
#pragma unroll
            for (int r = 0; r < 4; r++) {
                float xv = sx[r][k];
                aq[r] += xv * wq; ak[r] += xv * wk; av[r] += xv * wv;
            }
        }
#pragma unroll
        for (int r = 0; r < 4; r++) {
            red[0][ks][r][c] = aq[r];
            red[1][ks][r][c] = ak[r];
            red[2][ks][r][c] = av[r];
        }
        __syncthreads();
        int rr = t >> 7, cc = t & 127;
        float vq = 0, vk = 0, vv = 0;
#pragma unroll
        for (int s = 0; s < 4; s++) {
            vq += red[0][s][rr][cc];
            vk += red[1][s][rr][cc];
            vv += red[2][s][rr][cc];
        }
        Qf[(r0 + rr) * DDIM + cc] = (vq + bq[cc]) * 0.25f;
        Kf[(r0 + rr) * DDIM + cc] = vk + bk[cc];
        Vf[(r0 + rr) * DDIM + cc] = vv + bv[cc];
    } else {
        __shared__ float sWe[80];
        __shared__ float sbe[8];
        if (t < 80) sWe[t] = We[t];
        if (t < 8)  sbe[t] = be[t];
        __syncthreads();
        int u = (b - 512) * 512 + t;
        bool is64 = idx64(src);
        if (u < NN * 64 / 4) ((int4*)bm)[u] = make_int4(0, 0, 0, 0);
        if (u < NN) eid[(long)u * NN + u] = -2;
        if (u < NEDGE) {
            int s = is64 ? src[2 * u] : src[u];
            int d = is64 ? dst[2 * u] : dst[u];
            eid[(long)s * NN + d] = -2;
            eid[(long)d * NN + s] = -2;
            float ef[10];
#pragma unroll
            for (int k = 0; k < 10; k++) ef[k] = edge_feat[u * 10 + k];
#pragma unroll
            for (int h = 0; h < 8; h++) {
                float a = sbe[h];
#pragma unroll
                for (int k = 0; k < 10; k++) a += ef[k] * sWe[k * 8 + h];
                eb[u * 8 + h] = a;
            }
        }
    }
}

// ================= L2: scatter (R5-proven) =================
__global__ __launch_bounds__(512) void k_scatter(int* eid, unsigned* bm,
                                                 const int* src, const int* dst) {
    int t = blockIdx.x * blockDim.x + threadIdx.x;
    bool is64 = idx64(src);
    if (t < NEDGE) {
        int s = is64 ? src[2 * t] : src[t];
        int d = is64 ? dst[2 * t] : dst[t];
        atomicMax(&eid[(long)s * NN + d], t);
        atomicOr(&bm[s * 64 + (d >> 5)], 1u << (d & 31));
        atomicOr(&bm[d * 64 + (s >> 5)], 1u << (s & 31));
    } else if (t < NEDGE + NN) {
        int i = t - NEDGE;
        atomicOr(&bm[i * 64 + (i >> 5)], 1u << (i & 31));
    }
}

// ================= L3: attention (rows 4b..4b+3, 2 passes x 2 rows x 256thr) + tail =================
__global__ __launch_bounds__(512) void k_at(float* out, const float* Qf, const float* Kf,
                                            const float* Vf, const int* eid, const float* eb,
                                            const unsigned* bm,
                                            fp_c Wo, fp_c bo, fp_c node, fp_c g1, fp_c b1,
                                            fp_c W1, fp_c bf1, fp_c W2, fp_c bf2,
                                            fp_c g2, fp_c b2) {
    union Smem {
        struct { float qrow[2][DDIM]; int lj[2][CAP + 8]; int lev[2][CAP + 8];
                 float sc[2][CAP + 8][HH]; float hinv[2][HH];
                 float redpv[2][2][DDIM]; int scnt[2]; } a;                  // ~24 KB
        struct { float red[4][4][DDIM]; float x1[4][DDIM]; float sh[4][FFN];
                 float2 sc2[8]; } tl;                                        // ~18 KB
    };
    __shared__ Smem S;
    __shared__ float ao[4][DDIM];
    int b = blockIdx.x, t = threadIdx.x;

    // ----- attention: 2 passes, each 2 rows x 256 threads (R9-verified body) -----
    int gi = t >> 8;
    int t2 = t & 255;
#pragma unroll 1
    for (int p = 0; p < 2; p++) {
        __syncthreads();
        int il = p * 2 + gi;
        int i = b * 4 + il;
        if (t2 < 128) S.a.qrow[gi][t2] = Qf[i * DDIM + t2];
        if (t2 < 64) {
            unsigned word = bm[i * 64 + t2];
            int pc = __popc(word);
            int x = pc;
#pragma unroll
            for (int off = 1; off < 64; off <<= 1) {
                int y = __shfl_up(x, off);
                if (t2 >= off) x += y;
            }
            int cnt = __shfl(x, 63);
            if (cnt > CAP - 8) cnt = CAP - 8;
            int idx = x - pc;
            unsigned w = word;
            while (w && idx < CAP) {
                int bp = __ffs(w) - 1;
                S.a.lj[gi][idx++] = (t2 << 5) + bp;
                w &= w - 1;
            }
            if (t2 < 8) S.a.lj[gi][cnt + t2] = 0;
            if (t2 == 0) S.a.scnt[gi] = cnt;
        }
        __syncthreads();
        int cnt = S.a.scnt[gi];
        int cnt8 = (cnt + 7) & ~7;
        if (t2 < cnt8)
            S.a.lev[gi][t2] = (t2 < cnt) ? eid[(long)i * NN + S.a.lj[gi][t2]] : -1;
        __syncthreads();
        // scores: 32 slots x 8 heads
        {
            int h = t2 & 7, nsl = t2 >> 3;
            const float4* q4 = (const float4*)(&S.a.qrow[gi][h * DHH]);
            float4 q0 = q4[0], q1 = q4[1], q2 = q4[2], q3 = q4[3];
            for (int n = nsl; n < cnt8; n += 32) {
                int j = S.a.lj[gi][n];
                const float4* k4 = (const float4*)(Kf + j * DDIM + h * DHH);
                float4 k0 = k4[0], k1 = k4[1], k2 = k4[2], k3 = k4[3];
                float s = q0.x * k0.x + q0.y * k0.y + q0.z * k0.z + q0.w * k0.w
                        + q1.x * k1.x + q1.y * k1.y + q1.z * k1.z + q1.w * k1.w
                        + q2.x * k2.x + q2.y * k2.y + q2.z * k2.z + q2.w * k2.w
                        + q3.x * k3.x + q3.y * k3.y + q3.z * k3.z + q3.w * k3.w;
                int ev = S.a.lev[gi][n];
                if (ev >= 0) s += eb[ev * 8 + h];
                S.a.sc[gi][n][h] = s;
            }
        }
        __syncthreads();
        // softmax: 32 threads per head
        {
            int hh = t2 >> 5, sub = t2 & 31;
            float m = -1e30f;
            for (int n = sub; n < cnt; n += 32) m = fmaxf(m, S.a.sc[gi][n][hh]);
#pragma unroll
            for (int off = 1; off < 32; off <<= 1) m = fmaxf(m, __shfl_xor(m, off));
            float ssum = 0.f;
            for (int n = sub; n < cnt; n += 32) {
                float e = __expf(S.a.sc[gi][n][hh] - m);
                S.a.sc[gi][n][hh] = e;
                ssum += e;
            }
#pragma unroll
            for (int off = 1; off < 32; off <<= 1) ssum += __shfl_xor(ssum, off);
            if (sub == 0) S.a.hinv[gi][hh] = 1.0f / ssum;
        }
        if (t2 < 64) {
            int pp = cnt + (t2 >> 3);
            if (pp < cnt8) S.a.sc[gi][pp][t2 & 7] = 0.f;
        }
        __syncthreads();
        // PV: 2 groups of 128 threads
        {
            int gg = t2 >> 7, c = t2 & 127, h2 = c >> 4;
            float a = 0.f;
#pragma unroll 4
            for (int n = gg; n < cnt8; n += 2)
                a += S.a.sc[gi][n][h2] * Vf[S.a.lj[gi][n] * DDIM + c];
            S.a.redpv[gi][gg][c] = a;
        }
        __syncthreads();
        if (t2 < 128)
            ao[il][t2] = (S.a.redpv[gi][0][t2] + S.a.redpv[gi][1][t2]) * S.a.hinv[gi][t2 >> 4];
    }
    __syncthreads();

    // ----- tail: Wo+LN1 -> FFN1 -> FFN2+LN2 (R5-proven body, input = ao in LDS) -----
    int r0 = b * 4;
    int c = t & 127;
    int ks = t >> 7;
    int rr = t >> 7, cc = t & 127;
    // phase A
    {
        float acc[4] = {0, 0, 0, 0};
        int kbeg = ks * 32;
#pragma unroll 8
        for (int k = kbeg; k < kbeg + 32; k++) {
            float w = Wo[k * DDIM + c];
#pragma unroll
            for (int r = 0; r < 4; r++) acc[r] += ao[r][k] * w;
        }
#pragma unroll
        for (int r = 0; r < 4; r++) S.tl.red[ks][r][c] = acc[r];
        __syncthreads();
        float val = S.tl.red[0][rr][cc] + S.tl.red[1][rr][cc]
                  + S.tl.red[2][rr][cc] + S.tl.red[3][rr][cc];
        val += bo[cc] + node[(r0 + rr) * DDIM + cc];
        float vs = val, vq = val * val;
#pragma unroll
        for (int off = 32; off >= 1; off >>= 1) {
            vs += __shfl_down(vs, off);
            vq += __shfl_down(vq, off);
        }
        if ((t & 63) == 0) S.tl.sc2[t >> 6] = make_float2(vs, vq);
        __syncthreads();
        float sum = S.tl.sc2[2 * rr].x + S.tl.sc2[2 * rr + 1].x;
        float sq  = S.tl.sc2[2 * rr].y + S.tl.sc2[2 * rr + 1].y;
        float mu = sum * (1.0f / DDIM);
        float var = sq * (1.0f / DDIM) - mu * mu;
        S.tl.x1[rr][cc] = (val - mu) * rsqrtf(var + EPSV) * g1[cc] + b1[cc];
    }
    __syncthreads();
    // phase B
    {
        float acc[4] = {0, 0, 0, 0};
#pragma unroll 8
        for (int k = 0; k < DDIM; k++) {
            float w = W1[k * FFN + t];
#pragma unroll
            for (int r = 0; r < 4; r++) acc[r] += S.tl.x1[r][k] * w;
        }
        float bb = bf1[t];
#pragma unroll
        for (int r = 0; r < 4; r++) S.tl.sh[r][t] = fmaxf(acc[r] + bb, 0.f);
    }
    __syncthreads();
    // phase C
    {
        float acc[4] = {0, 0, 0, 0};
        int kbeg = ks * 128;
#pragma unroll 8
        for (int k = kbeg; k < kbeg + 128; k++) {
            float w = W2[k * DDIM + c];
#pragma unroll
            for (int r = 0; r < 4; r++) acc[r] += S.tl.sh[r][k] * w;
        }
#pragma unroll
        for (int r = 0; r < 4; r++) S.tl.red[ks][r][c] = acc[r];
        __syncthreads();
        float val = S.tl.red[0][rr][cc] + S.tl.red[1][rr][cc]
                  + S.tl.red[2][rr][cc] + S.tl.red[3][rr][cc];
        val += bf2[cc] + S.tl.x1[rr][cc];
        float vs = val, vq = val * val;
#pragma unroll
        for (int off = 32; off >= 1; off >>= 1) {
            vs += __shfl_down(vs, off);
            vq += __shfl_down(vq, off);
        }
        if ((t & 63) == 0) S.tl.sc2[t >> 6] = make_float2(vs, vq);
        __syncthreads();
        float sum = S.tl.sc2[2 * rr].x + S.tl.sc2[2 * rr + 1].x;
        float sq  = S.tl.sc2[2 * rr].y + S.tl.sc2[2 * rr + 1].y;
        float mu = sum * (1.0f / DDIM);
        float var = sq * (1.0f / DDIM) - mu * mu;
        out[(r0 + rr) * DDIM + cc] = (val - mu) * rsqrtf(var + EPSV) * g2[cc] + b2[cc];
    }
}

extern "C" void kernel_launch(void* const* d_in, const int* in_sizes, int n_in,
                              void* d_out, int out_size, void* d_ws, size_t ws_size,
                              hipStream_t stream) {
    fp_c node = (fp_c)d_in[0];
    fp_c edge_feat = (fp_c)d_in[1];
    const int* src = (const int*)d_in[2];
    const int* dst = (const int*)d_in[3];
    fp_c Wq = (fp_c)d_in[4];  fp_c bq = (fp_c)d_in[5];
    fp_c Wk = (fp_c)d_in[6];  fp_c bk = (fp_c)d_in[7];
    fp_c Wv = (fp_c)d_in[8];  fp_c bv = (fp_c)d_in[9];
    fp_c Wo = (fp_c)d_in[10]; fp_c bo = (fp_c)d_in[11];
    fp_c We = (fp_c)d_in[12]; fp_c be = (fp_c)d_in[13];
    fp_c g1 = (fp_c)d_in[14]; fp_c b1n = (fp_c)d_in[15];
    fp_c g2 = (fp_c)d_in[16]; fp_c b2n = (fp_c)d_in[17];
    fp_c W1 = (fp_c)d_in[18]; fp_c bf1 = (fp_c)d_in[19];
    fp_c W2 = (fp_c)d_in[20]; fp_c bf2 = (fp_c)d_in[21];

    char* ws = (char*)d_ws;
    int* eid     = (int*)ws;      ws += (size_t)NN * NN * 4;     // 16.8 MB
    unsigned* bm = (unsigned*)ws; ws += (size_t)NN * 64 * 4;     // 512 KB
    float* eb    = (float*)ws;    ws += (size_t)NEDGE * 8 * 4;   // 2 MB
    float* Qf    = (float*)ws;    ws += (size_t)NN * DDIM * 4;
    float* Kf    = (float*)ws;    ws += (size_t)NN * DDIM * 4;
    float* Vf    = (float*)ws;    ws += (size_t)NN * DDIM * 4;

    k_pq<<<768, 512, 0, stream>>>(Qf, Kf, Vf, node, Wq, bq, Wk, bk, Wv, bv,
                                  eid, bm, eb, src, dst, edge_feat, We, be);
    k_scatter<<<(NEDGE + NN + 511) / 512, 512, 0, stream>>>(eid, bm, src, dst);
    k_at<<<NN / 4, 512, 0, stream>>>((float*)d_out, Qf, Kf, Vf, eid, eb, bm,
                                     Wo, bo, node, g1, b1n, W1, bf1, W2, bf2, g2, b2n);
}

// Round 12
// 69.302 us; speedup vs baseline: 2.0870x; 1.0306x over previous
//
#include <hip/hip_runtime.h>
#include <hip/hip_bf16.h>

#define NN   2048
#define DDIM 128
#define HH    8
#define DHH  16
#define NEDGE 65536
#define FFN  512
#define EPSV 1e-5f
#define CAP  256
#define SCP  9   // padded stride for sc[] (coprime with 32 banks)

typedef const float* fp_c;

// int64 vs int32 index layout: int64 values < 2048 have all-zero odd words.
__device__ __forceinline__ bool idx64(const int* src) {
    return (src[1] | src[3] | src[5] | src[7] | src[9] | src[11]) == 0;
}

// ================= L1: fused prep + QKV =================
// blocks 0..511: QKV GEMM rows 4b..4b+3.
// blocks 512..767: prep — full streaming eid clear (-2), bm clear, edge-bias GEMM.
__global__ __launch_bounds__(512) void k_pq(float* Qf, float* Kf, float* Vf, fp_c x,
                                            fp_c Wq, fp_c bq, fp_c Wk, fp_c bk, fp_c Wv, fp_c bv,
                                            int* eid, unsigned* bm, float* eb,
                                            const int* src, const int* dst,
                                            fp_c edge_feat, fp_c We, fp_c be) {
    int b = blockIdx.x;
    int t = threadIdx.x;
    if (b < 512) {
        __shared__ float sx[4][DDIM];
        __shared__ float red[3][4][4][DDIM];
        int r0 = b * 4;
        int c = t & 127;
        int ks = t >> 7;
        sx[ks][c] = x[r0 * DDIM + t];
        __syncthreads();
        float aq[4] = {0, 0, 0, 0}, ak[4] = {0, 0, 0, 0}, av[4] = {0, 0, 0, 0};
        int kbeg = ks * 32;
#pragma unroll 8
        for (int k = kbeg; k < kbeg + 32; k++) {
            float wq = Wq[k * DDIM + c];
            float wk = Wk[k * DDIM + c];
            float wv = Wv[k * DDIM + c];
#pragma unroll
            for (int r = 0; r < 4; r++) {
                float xv = sx[r][k];
                aq[r] += xv * wq; ak[r] += xv * wk; av[r] += xv * wv;
            }
        }
#pragma unroll
        for (int r = 0; r < 4; r++) {
            red[0][ks][r][c] = aq[r];
            red[1][ks][r][c] = ak[r];
            red[2][ks][r][c] = av[r];
        }
        __syncthreads();
        int rr = t >> 7, cc = t & 127;
        float vq = 0, vk = 0, vv = 0;
#pragma unroll
        for (int s = 0; s < 4; s++) {
            vq += red[0][s][rr][cc];
            vk += red[1][s][rr][cc];
            vv += red[2][s][rr][cc];
        }
        Qf[(r0 + rr) * DDIM + cc] = (vq + bq[cc]) * 0.25f;
        Kf[(r0 + rr) * DDIM + cc] = vk + bk[cc];
        Vf[(r0 + rr) * DDIM + cc] = vv + bv[cc];
    } else {
        __shared__ float sWe[80];
        __shared__ float sbe[8];
        if (t < 80) sWe[t] = We[t];
        if (t < 8)  sbe[t] = be[t];
        __syncthreads();
        int pb = b - 512;                      // 0..255
        // full eid clear to -2: 2048*2048 ints = 1048576 int4 / 256 blocks = 4096/block
        long base = (long)pb * 4096;
        int4 m2 = make_int4(-2, -2, -2, -2);
#pragma unroll
        for (int q = 0; q < 8; q++)
            ((int4*)eid)[base + q * 512 + t] = m2;
        int u = pb * 512 + t;                  // 0..131071
        if (u < NN * 64 / 4) ((int4*)bm)[u] = make_int4(0, 0, 0, 0);
        if (u < NEDGE) {
            float ef[10];
#pragma unroll
            for (int k = 0; k < 10; k++) ef[k] = edge_feat[u * 10 + k];
#pragma unroll
            for (int h = 0; h < 8; h++) {
                float a = sbe[h];
#pragma unroll
                for (int k = 0; k < 10; k++) a += ef[k] * sWe[k * 8 + h];
                eb[u * 8 + h] = a;
            }
        }
    }
}

// ================= L2: scatter (bitmap OR + eid atomicMax = last-wins) =================
__global__ __launch_bounds__(512) void k_scatter(int* eid, unsigned* bm,
                                                 const int* src, const int* dst) {
    int t = blockIdx.x * blockDim.x + threadIdx.x;
    bool is64 = idx64(src);
    if (t < NEDGE) {
        int s = is64 ? src[2 * t] : src[t];
        int d = is64 ? dst[2 * t] : dst[t];
        atomicMax(&eid[(long)s * NN + d], t);
        atomicOr(&bm[s * 64 + (d >> 5)], 1u << (d & 31));
        atomicOr(&bm[d * 64 + (s >> 5)], 1u << (s & 31));
    } else if (t < NEDGE + NN) {
        int i = t - NEDGE;
        atomicOr(&bm[i * 64 + (i >> 5)], 1u << (i & 31));
    }
}

// ================= L3: sparse masked attention — 2048 blocks x 256 threads =================
__global__ __launch_bounds__(256) void k_attn(float* attn_out, const float* Qf, const float* Kf,
                                              const float* Vf, const int* eid, const float* eb,
                                              const unsigned* bm) {
    __shared__ float qrow[DDIM];
    __shared__ int   lj[CAP + 8];
    __shared__ int   lev[CAP + 8];
    __shared__ float sc[CAP + 8][SCP];   // stride 9: conflict-free softmax
    __shared__ float hinv[HH];
    __shared__ float redpv[2][DDIM];
    __shared__ int   scnt;
    int i = blockIdx.x;
    int t = threadIdx.x;
    if (t < 128) qrow[t] = Qf[i * DDIM + t];

    // phase 1 (wave 0): bitmap -> compacted neighbor list (ascending j)
    if (t < 64) {
        unsigned word = bm[i * 64 + t];
        int pc = __popc(word);
        int x = pc;
#pragma unroll
        for (int off = 1; off < 64; off <<= 1) {
            int y = __shfl_up(x, off);
            if (t >= off) x += y;
        }
        int cnt = __shfl(x, 63);
        if (cnt > CAP - 8) cnt = CAP - 8;
        int idx = x - pc;
        unsigned w = word;
        while (w && idx < CAP) {
            int bp = __ffs(w) - 1;
            lj[idx++] = (t << 5) + bp;
            w &= w - 1;
        }
        if (t < 8) lj[cnt + t] = 0;  // pad
        if (t == 0) scnt = cnt;
    }
    __syncthreads();
    int cnt = scnt;
    int cnt8 = (cnt + 7) & ~7;
    // bias-id gather (L2-resident eid after streaming clear)
    if (t < cnt8) lev[t] = (t < cnt) ? eid[(long)i * NN + lj[t]] : -1;
    __syncthreads();

    // phase 2: scores — 32 neighbor slots x 8 heads in parallel
    int h = t & 7;
    int nsl = t >> 3;
    const float4* q4 = (const float4*)(qrow + h * DHH);
    float4 q0 = q4[0], q1 = q4[1], q2 = q4[2], q3 = q4[3];
    for (int n = nsl; n < cnt8; n += 32) {
        int j = lj[n];
        const float4* k4 = (const float4*)(Kf + j * DDIM + h * DHH);
        float4 k0 = k4[0], k1 = k4[1], k2 = k4[2], k3 = k4[3];
        float s = q0.x * k0.x + q0.y * k0.y + q0.z * k0.z + q0.w * k0.w
                + q1.x * k1.x + q1.y * k1.y + q1.z * k1.z + q1.w * k1.w
                + q2.x * k2.x + q2.y * k2.y + q2.z * k2.z + q2.w * k2.w
                + q3.x * k3.x + q3.y * k3.y + q3.z * k3.z + q3.w * k3.w;
        int ev = lev[n];
        if (ev >= 0) s += eb[ev * 8 + h];
        sc[n][h] = s;
    }
    __syncthreads();

    // phase 3: per-head softmax — 32 threads per head
    {
        int hh = t >> 5, sub = t & 31;
        float m = -1e30f;
        for (int n = sub; n < cnt; n += 32) m = fmaxf(m, sc[n][hh]);
#pragma unroll
        for (int off = 1; off < 32; off <<= 1) m = fmaxf(m, __shfl_xor(m, off));
        float ssum = 0.f;
        for (int n = sub; n < cnt; n += 32) {
            float e = __expf(sc[n][hh] - m);
            sc[n][hh] = e;
            ssum += e;
        }
#pragma unroll
        for (int off = 1; off < 32; off <<= 1) ssum += __shfl_xor(ssum, off);
        if (sub == 0) hinv[hh] = 1.0f / ssum;
    }
    // zero pad rows
    if (t < 64) {
        int p = cnt + (t >> 3);
        if (p < cnt8) sc[p][t & 7] = 0.f;
    }
    __syncthreads();

    // phase 4: PV — neighbors split across 2 groups of 128 threads
    {
        int g = t >> 7, c = t & 127, h2 = c >> 4;
        float a = 0.f;
#pragma unroll 4
        for (int n = g; n < cnt8; n += 2)
            a += sc[n][h2] * Vf[lj[n] * DDIM + c];
        redpv[g][c] = a;
    }
    __syncthreads();
    if (t < 128)
        attn_out[i * DDIM + t] = (redpv[0][t] + redpv[1][t]) * hinv[t >> 4];
}

// ================= L4: fused tail — Wo+LN1 -> FFN1 -> FFN2+LN2, ROWS=4 =================
__global__ __launch_bounds__(512) void k_tail(float* out, const float* ain,
                                              fp_c Wo, fp_c bo, fp_c node, fp_c g1, fp_c b1,
                                              fp_c W1, fp_c bf1, fp_c W2, fp_c bf2,
                                              fp_c g2, fp_c b2) {
    __shared__ float sa[4][DDIM];
    __shared__ float red[4][4][DDIM];
    __shared__ float x1ld[4][DDIM];
    __shared__ float sh[4][FFN];
    __shared__ float2 sc2[8];
    int t = threadIdx.x;
    int r0 = blockIdx.x * 4;
    int c = t & 127;
    int ks = t >> 7;
    int rr = t >> 7, cc = t & 127;
    sa[rr][cc] = ain[r0 * DDIM + t];
    __syncthreads();

    // phase A: Wo proj (K-split 4) + bias + residual + LN1 -> x1ld
    {
        float acc[4] = {0, 0, 0, 0};
        int kbeg = ks * 32;
#pragma unroll 8
        for (int k = kbeg; k < kbeg + 32; k++) {
            float w = Wo[k * DDIM + c];
#pragma unroll
            for (int r = 0; r < 4; r++) acc[r] += sa[r][k] * w;
        }
#pragma unroll
        for (int r = 0; r < 4; r++) red[ks][r][c] = acc[r];
        __syncthreads();
        float val = red[0][rr][cc] + red[1][rr][cc] + red[2][rr][cc] + red[3][rr][cc];
        val += bo[cc] + node[(r0 + rr) * DDIM + cc];
        float vs = val, vq = val * val;
#pragma unroll
        for (int off = 32; off >= 1; off >>= 1) {
            vs += __shfl_down(vs, off);
            vq += __shfl_down(vq, off);
        }
        if ((t & 63) == 0) sc2[t >> 6] = make_float2(vs, vq);
        __syncthreads();
        float sum = sc2[2 * rr].x + sc2[2 * rr + 1].x;
        float sq  = sc2[2 * rr].y + sc2[2 * rr + 1].y;
        float mu = sum * (1.0f / DDIM);
        float var = sq * (1.0f / DDIM) - mu * mu;
        x1ld[rr][cc] = (val - mu) * rsqrtf(var + EPSV) * g1[cc] + b1[cc];
    }
    __syncthreads();

    // phase B: hidden = relu(x1 @ W1 + bf1), column t of 512
    {
        float acc[4] = {0, 0, 0, 0};
#pragma unroll 8
        for (int k = 0; k < DDIM; k++) {
            float w = W1[k * FFN + t];
#pragma unroll
            for (int r = 0; r < 4; r++) acc[r] += x1ld[r][k] * w;
        }
        float bb = bf1[t];
#pragma unroll
        for (int r = 0; r < 4; r++) sh[r][t] = fmaxf(acc[r] + bb, 0.f);
    }
    __syncthreads();

    // phase C: ffn2 (K-split 4 over 512) + bias + residual + LN2 -> out
    {
        float acc[4] = {0, 0, 0, 0};
        int kbeg = ks * 128;
#pragma unroll 8
        for (int k = kbeg; k < kbeg + 128; k++) {
            float w = W2[k * DDIM + c];
#pragma unroll
            for (int r = 0; r < 4; r++) acc[r] += sh[r][k] * w;
        }
#pragma unroll
        for (int r = 0; r < 4; r++) red[ks][r][c] = acc[r];
        __syncthreads();
        float val = red[0][rr][cc] + red[1][rr][cc] + red[2][rr][cc] + red[3][rr][cc];
        val += bf2[cc] + x1ld[rr][cc];
        float vs = val, vq = val * val;
#pragma unroll
        for (int off = 32; off >= 1; off >>= 1) {
            vs += __shfl_down(vs, off);
            vq += __shfl_down(vq, off);
        }
        if ((t & 63) == 0) sc2[t >> 6] = make_float2(vs, vq);
        __syncthreads();
        float sum = sc2[2 * rr].x + sc2[2 * rr + 1].x;
        float sq  = sc2[2 * rr].y + sc2[2 * rr + 1].y;
        float mu = sum * (1.0f / DDIM);
        float var = sq * (1.0f / DDIM) - mu * mu;
        out[(r0 + rr) * DDIM + cc] = (val - mu) * rsqrtf(var + EPSV) * g2[cc] + b2[cc];
    }
}

extern "C" void kernel_launch(void* const* d_in, const int* in_sizes, int n_in,
                              void* d_out, int out_size, void* d_ws, size_t ws_size,
                              hipStream_t stream) {
    fp_c node = (fp_c)d_in[0];
    fp_c edge_feat = (fp_c)d_in[1];
    const int* src = (const int*)d_in[2];
    const int* dst = (const int*)d_in[3];
    fp_c Wq = (fp_c)d_in[4];  fp_c bq = (fp_c)d_in[5];
    fp_c Wk = (fp_c)d_in[6];  fp_c bk = (fp_c)d_in[7];
    fp_c Wv = (fp_c)d_in[8];  fp_c bv = (fp_c)d_in[9];
    fp_c Wo = (fp_c)d_in[10]; fp_c bo = (fp_c)d_in[11];
    fp_c We = (fp_c)d_in[12]; fp_c be = (fp_c)d_in[13];
    fp_c g1 = (fp_c)d_in[14]; fp_c b1n = (fp_c)d_in[15];
    fp_c g2 = (fp_c)d_in[16]; fp_c b2n = (fp_c)d_in[17];
    fp_c W1 = (fp_c)d_in[18]; fp_c bf1 = (fp_c)d_in[19];
    fp_c W2 = (fp_c)d_in[20]; fp_c bf2 = (fp_c)d_in[21];

    char* ws = (char*)d_ws;
    int* eid     = (int*)ws;      ws += (size_t)NN * NN * 4;     // 16.8 MB
    unsigned* bm = (unsigned*)ws; ws += (size_t)NN * 64 * 4;     // 512 KB
    float* eb    = (float*)ws;    ws += (size_t)NEDGE * 8 * 4;   // 2 MB
    float* Qf    = (float*)ws;    ws += (size_t)NN * DDIM * 4;
    float* Kf    = (float*)ws;    ws += (size_t)NN * DDIM * 4;
    float* Vf    = (float*)ws;    ws += (size_t)NN * DDIM * 4;
    float* attn_o= (float*)ws;    ws += (size_t)NN * DDIM * 4;

    k_pq<<<768, 512, 0, stream>>>(Qf, Kf, Vf, node, Wq, bq, Wk, bk, Wv, bv,
                                  eid, bm, eb, src, dst, edge_feat, We, be);
    k_scatter<<<(NEDGE + NN + 511) / 512, 512, 0, stream>>>(eid, bm, src, dst);
    k_attn<<<NN, 256, 0, stream>>>(attn_o, Qf, Kf, Vf, eid, eb, bm);
    k_tail<<<NN / 4, 512, 0, stream>>>((float*)d_out, attn_o, Wo, bo, node, g1, b1n,
                                       W1, bf1, W2, bf2, g2, b2n);
}